// Round 9
// baseline (265.377 us; speedup 1.0000x reference)
//
#include <hip/hip_runtime.h>
#include <math.h>

#define B_ 8
#define T_ 4096
#define M_ 1024
#define TT 32          // rows per block tile; grid = B_ * (T_/TT) = 1024 blocks
#define CH 8           // chunk rows: 8 independent loads in flight per wave
#define EPSF 1e-6f

typedef float fvec4 __attribute__((ext_vector_type(4)));

// 16-tap causal bump convolution along T + per-channel softplus gate.
// out[b,t,m] = gate[m] * (1/S_t) * sum_{d=0}^{15} w[d] * x[b,t-d,m]
//
// Round-8 post-mortem: guaranteed deep MLP (19 hardware-queued global_load_lds
// per wave, LDS staged, no VGPR battle) changed NOTHING — 83 us, 2.42 TB/s,
// same as the register ring and the flat tile. Read-side theories are dead.
// The cross-round invariant: nt-store write rate is pinned at 1.53-1.67 TB/s
// across ALL structures and read loads, and duration == WRITE bytes / 1.6
// everywhere (131 MB / 1.6 = 82 us = our floor). m13 copy (3.15 TB/s write)
// and m146 RMSNorm (4.89 TB/s mixed, plain stores) prove the hardware can do
// better -> the nt store path itself is the suspected cap.
// r7's plain-store test was confounded: the flat-tile host pushes 385 MB of
// staged re-reads through L2, colliding with plain stores' 131 MB
// write-allocate stream in TCC. The ring structure reads each line ONCE
// (lowest L2 pressure) — the clean host for the plain-store A/B.
//
// THIS ROUND (single variable vs round 3's 83-us kernel): nt -> PLAIN stores.
__global__ __launch_bounds__(256) void bump_conv_kernel(
    const float* __restrict__ x,
    const float* __restrict__ gate_raw,
    float* __restrict__ out) {
  const int tiles = T_ / TT;               // 128
  // XCD-aware bijective swizzle (nwg = 1024, 1024 % 8 == 0).
  const int nwg = B_ * tiles;              // 1024
  const int cpx = nwg / 8;                 // 128
  const int lin = ((int)blockIdx.x % 8) * cpx + (int)blockIdx.x / 8;
  const int tile = lin % tiles;
  const int b    = lin / tiles;
  const int t0   = tile * TT;              // multiple of 16 -> ring slot = t & 15
  const int m    = threadIdx.x * 4;        // 256 threads * float4 = M_

  // --- taps ---
  float w[16];
  float S = 0.0f;
#pragma unroll
  for (int d = 0; d < 16; ++d) {
    float u = fminf((float)d * (1.0f / 15.0f), 1.0f - EPSF);
    float den = 1.0f - u * u + EPSF;
    w[d] = expf(1.0f - 1.0f / den);        // d=15 -> expf(-3.3e5) == 0.0f
    S += w[d];
  }
  const float rsS = 1.0f / fmaxf(S, EPSF);

  // --- per-channel gate: softplus(gate_raw) ---
  const fvec4 graw = *(const fvec4*)(gate_raw + m);
  fvec4 g;
  g.x = fmaxf(graw.x, 0.0f) + log1pf(expf(-fabsf(graw.x)));
  g.y = fmaxf(graw.y, 0.0f) + log1pf(expf(-fabsf(graw.y)));
  g.z = fmaxf(graw.z, 0.0f) + log1pf(expf(-fabsf(graw.z)));
  g.w = fmaxf(graw.w, 0.0f) + log1pf(expf(-fabsf(graw.w)));

  const float* xb = x   + (size_t)b * T_ * M_ + m;
  float*       ob = out + (size_t)b * T_ * M_ + m;

  // --- ring buffer: slot for row t is (t & 15) ---
  fvec4 r[16];
  r[0] = (fvec4)(0.f);
#pragma unroll
  for (int k = 1; k <= 15; ++k) {          // halo rows t0-15 .. t0-1 -> slots 1..15
    const int t = t0 - 16 + k;
    r[k] = (t >= 0) ? *(const fvec4*)(xb + (size_t)t * M_)
                    : (fvec4)(0.f);
  }

  // --- chunk double-buffer in registers; all indices static after unroll ---
  fvec4 pb[2][CH];
#pragma unroll
  for (int s = 0; s < CH; ++s)             // chunk 0: 8 independent loads
    pb[0][s] = *(const fvec4*)(xb + (size_t)(t0 + s) * M_);

#pragma unroll
  for (int c = 0; c < TT / CH; ++c) {      // 4 chunks, fully unrolled
    const int cur = c & 1;
    const int nxb = cur ^ 1;
    const int tc  = t0 + c * CH;

    if (c + 1 < TT / CH) {                 // issue next chunk's 8 loads
#pragma unroll
      for (int s = 0; s < CH; ++s)
        pb[nxb][s] = *(const fvec4*)(xb + (size_t)(tc + CH + s) * M_);
    }

#pragma unroll
    for (int s = 0; s < CH; ++s) {
      const int t = tc + s;
      r[(c * CH + s) & 15] = pb[cur][s];   // slot (t & 15); static index

      float ax = 0.f, ay = 0.f, az = 0.f, aw = 0.f;
#pragma unroll
      for (int d = 0; d < 16; ++d) {
        const fvec4 v = r[((c * CH + s) - d + 16) & 15];  // static index
        const float wd = w[d];
        ax = fmaf(wd, v.x, ax);
        ay = fmaf(wd, v.y, ay);
        az = fmaf(wd, v.z, az);
        aw = fmaf(wd, v.w, aw);
      }

      float sc = rsS;
      if (t < 15) {                        // wave-uniform; only tile 0
        float p = 0.0f;
#pragma unroll
        for (int d = 0; d < 16; ++d) p += (d <= t) ? w[d] : 0.0f;
        sc = 1.0f / fmaxf(p, EPSF);
      }

      fvec4 o;
      o.x = ax * sc * g.x;
      o.y = ay * sc * g.y;
      o.z = az * sc * g.z;
      o.w = aw * sc * g.w;
      // PLAIN store — the single variable vs round 3 (which used nt).
      // Ring host = minimal L2 read pressure, so the write-allocate path
      // gets the L2/L3 combining benefit without read collision.
      *(fvec4*)(ob + (size_t)t * M_) = o;
    }
  }
}

extern "C" void kernel_launch(void* const* d_in, const int* in_sizes, int n_in,
                              void* d_out, int out_size, void* d_ws, size_t ws_size,
                              hipStream_t stream) {
  const float* x         = (const float*)d_in[0];
  // d_in[1] = mask (T,T): redundant (taps already causal) -- intentionally unread.
  const float* gate_raw  = (const float*)d_in[2];
  float*       out       = (float*)d_out;

  dim3 grid(B_ * (T_ / TT));   // 1024 blocks
  dim3 block(256);
  bump_conv_kernel<<<grid, block, 0, stream>>>(x, gate_raw, out);
}